// Round 15
// baseline (170.677 us; speedup 1.0000x reference)
//
#include <hip/hip_runtime.h>
#include <stdint.h>

using f32x4  = __attribute__((ext_vector_type(4))) float;
using short8 = __attribute__((ext_vector_type(8))) short;

#define DEVI static __device__ __forceinline__

// float -> bf16 round-to-nearest-even
DEVI unsigned short f2bf(float f) {
  unsigned u = __float_as_uint(f);
  u += 0x7FFFu + ((u >> 16) & 1u);
  return (unsigned short)(u >> 16);
}

// async global->LDS, 16B per lane. LDS dest is wave-uniform base; HW writes
// base + lane*16. Global src is per-lane.
DEVI void gld16(const void* g, void* l) {
  __builtin_amdgcn_global_load_lds(
      reinterpret_cast<const __attribute__((address_space(1))) unsigned int*>(
          reinterpret_cast<uintptr_t>(g)),
      reinterpret_cast<__attribute__((address_space(3))) unsigned int*>(
          reinterpret_cast<uintptr_t>(l)),
      16, 0, 0);
}

// ---------------- K1: per-(b,c) sum/sumsq of x; block 0 zeroes bn/ctr/zp ----
__global__ __launch_bounds__(256) void k_stats(const float* __restrict__ x,
                                               float* __restrict__ sums,
                                               float* __restrict__ sumsq,
                                               float* __restrict__ bn,
                                               int* __restrict__ ctr,
                                               float* __restrict__ zp) {
  const int bc = blockIdx.x;  // 0..12287
  if (bc == 0) {              // fold former k_zero here (runs before k_conv)
    const int t = threadIdx.x;
    for (int i = t; i < 768; i += 256) bn[i] = 0.0f;
    for (int i = t; i < 1024; i += 256) zp[i] = 0.0f;
    if (t < 4) ctr[t] = 0;
  }
  const float4 v =
      reinterpret_cast<const float4*>(x + (size_t)bc * 1024)[threadIdx.x];
  float s = v.x + v.y + v.z + v.w;
  float q = v.x * v.x + v.y * v.y + v.z * v.z + v.w * v.w;
#pragma unroll
  for (int off = 1; off < 64; off <<= 1) {
    s += __shfl_xor(s, off, 64);
    q += __shfl_xor(q, off, 64);
  }
  __shared__ float ls[4], lq[4];
  const int wv = threadIdx.x >> 6;
  if ((threadIdx.x & 63) == 0) { ls[wv] = s; lq[wv] = q; }
  __syncthreads();
  if (threadIdx.x == 0) {
    sums[bc]  = ls[0] + ls[1] + ls[2] + ls[3];
    sumsq[bc] = lq[0] + lq[1] + lq[2] + lq[3];
  }
}

// ---------------- K2: fold both CSA blocks into fea2 = A*x + B ----------------
__global__ __launch_bounds__(384) void k_coef(
    const float* __restrict__ pmp, const float* __restrict__ psp,
    const float* __restrict__ pmn, const float* __restrict__ psn,
    const float* __restrict__ cw, const int* __restrict__ label,
    const float* __restrict__ sums, const float* __restrict__ sumsq,
    float* __restrict__ Ac, float* __restrict__ Bc) {
  const int b = blockIdx.x;    // 0..31
  const int c = threadIdx.x;   // 0..383
  __shared__ float w0[64], w1[64];
  if (threadIdx.x < 64) w0[threadIdx.x] = cw[b * 64 + threadIdx.x];
  else if (threadIdx.x < 128) w1[threadIdx.x - 64] = cw[2048 + b * 64 + (threadIdx.x - 64)];
  __syncthreads();
  const bool sel = (label[b] == 0);
  const float* m1t = (sel ? pmp : pmn);           // layer 0 tables [K=64][C=384]
  const float* s1t = (sel ? psp : psn);
  const float* m2t = m1t + 64 * 384;              // layer 1
  const float* s2t = s1t + 64 * 384;
  float m1 = 0.f, s1 = 0.f, m2 = 0.f, s2 = 0.f;
  for (int k = 0; k < 64; ++k) {
    const float a0 = w0[k], a1 = w1[k];
    m1 += a0 * m1t[k * 384 + c];
    s1 += a0 * s1t[k * 384 + c];
    m2 += a1 * m2t[k * 384 + c];
    s2 += a1 * s2t[k * 384 + c];
  }
  const int bc = b * 384 + c;
  const float sum = sums[bc], sq = sumsq[bc];
  const float mean = sum * (1.0f / 1024.0f);
  float var = (sq - sum * mean) * (1.0f / 1023.0f);  // ddof=1
  var = fmaxf(var, 0.0f);
  const float sd1 = sqrtf(var + 1e-5f);
  const float a1c = 1.0f + s1 / sd1;
  const float b1c = m1 - mean * (s1 / sd1);
  const float mean1 = a1c * mean + b1c;      // exact mean of affine fea1
  const float var1  = a1c * a1c * var;       // exact ddof=1 var of affine fea1
  const float sd2 = sqrtf(var1 + 1e-5f);
  const float t2 = 1.0f + s2 / sd2;
  Ac[bc] = a1c * t2;
  Bc[bc] = b1c * t2 + m2 - mean1 * (s2 / sd2);
}

// ---------------- K3: fea2 NHWC bf16 = A*x + B (LDS transpose for writes) ----
// grid (128,6): block = 256 pixels x 64 channels
__global__ __launch_bounds__(256) void k_fea(const float* __restrict__ x,
                                             const float* __restrict__ Ac,
                                             const float* __restrict__ Bc,
                                             unsigned short* __restrict__ fea) {
  __shared__ unsigned short tb[256][68];   // +4 pad: bank-conflict-free
  const int t = threadIdx.x;
  const int g0 = blockIdx.x << 8;          // pixel base
  const int b = g0 >> 10;                  // uniform per block
  const int c0 = blockIdx.y * 64;
  const float* xb = x + (((size_t)b * 384) << 10) + (g0 & 1023) + t;
  const float* Ab = Ac + b * 384 + c0;
  const float* Bb = Bc + b * 384 + c0;
#pragma unroll 1
  for (int u8 = 0; u8 < 64; u8 += 8) {
    union { unsigned short us[8]; uint4 v; } pk;
#pragma unroll
    for (int u = 0; u < 8; ++u) {
      const int c = u8 + u;
      pk.us[u] = f2bf(Ab[c] * xb[(size_t)(c0 + c) << 10] + Bb[c]);
    }
    *reinterpret_cast<uint4*>(&tb[t][u8]) = pk.v;
  }
  __syncthreads();
  const int j = t & 7;
#pragma unroll
  for (int rep = 0; rep < 8; ++rep) {
    const int p = rep * 32 + (t >> 3);
    const uint4 v = *reinterpret_cast<const uint4*>(&tb[p][j * 8]);
    *reinterpret_cast<uint4*>(fea + (size_t)(g0 + p) * 384 + c0 + j * 8) = v;
  }
}

// ---------------- K4: conv_w (OIHW f32) -> wb2 pre-staged order ----------------
// wb2 = [ct(4)][step(36)=cc*3+dy][slab(18)][lane(64)][8 bf16].
// Slab row r = slab*16 + (lane>>2) = dxl*96 + co_l; tap = dy*3 + dxl;
// grp g=lane&3 holds data grp dd = g ^ ((co_l>>1)&3); ci = cc*32 + dd*8 + u.
__global__ __launch_bounds__(256) void k_wcvt(const float* __restrict__ w,
                                              unsigned short* __restrict__ wb2) {
  const int g = blockIdx.x * 256 + threadIdx.x;  // 0..165887
  const int ct = g / 41472;
  const int r1 = g - ct * 41472;
  const int step = r1 / 1152;
  const int r2 = r1 - step * 1152;
  const int slab = r2 >> 6;
  const int lane = r2 & 63;
  const int cc = step / 3, dy = step - cc * 3;
  const int r = slab * 16 + (lane >> 2);         // 0..287
  const int dxl = r / 96, co_l = r - dxl * 96;
  const int dd = (lane & 3) ^ ((co_l >> 1) & 3);
  const int tap = dy * 3 + dxl;
  const int co = ct * 96 + co_l;
  const int cib = cc * 32 + dd * 8;
  union { unsigned short us[8]; uint4 v4; } pk;
#pragma unroll
  for (int u = 0; u < 8; ++u)
    pk.us[u] = f2bf(w[(size_t)(co * 384 + cib + u) * 9 + tap]);
  *reinterpret_cast<uint4*>(wb2 + (size_t)g * 8) = pk.v4;
}

// ---------------- K5: implicit-GEMM conv + BN stats + FUSED BN finalize ----
// R14 base + ROLLING dx-level fragment double-buffer: two fragment sets A/B
// (112 VGPR); every 48-MFMA dx-block issues the NEXT block's 14 ds_reads
// before its MFMAs (independent -> scheduler interleaves; lgkm satisfied
// ~900cyc later). Step-boundary af from skew-2-resident W[st+1]; bf fresh
// post-barrier on chunk changes (dy==2). cc-loop unrolled x2 for set parity.
__global__ __launch_bounds__(256, 1) void k_conv(
    const unsigned short* __restrict__ fea, const unsigned short* __restrict__ wb2,
    const unsigned short* __restrict__ zpg, float* __restrict__ out,
    float* __restrict__ bn_sum, float* __restrict__ bn_sq,
    const float* __restrict__ gamma, const float* __restrict__ beta,
    int* __restrict__ ctr) {
  __shared__ __align__(16) unsigned char lds[129024];
  const int tid = threadIdx.x;
  const int lane = tid & 63, wv = tid >> 6;
  const int pt = blockIdx.x;      // 0..63
  const int ct = blockIdx.y;      // 0..3
  const int b = pt >> 1, h0 = (pt & 1) * 16;
  const int co0 = ct * 96;
  const int wn = wv;              // pixel quarter (128 px = 4 rows each)

  // ---- hoisted LDS read addresses ----
  const int l15 = lane & 15, d = lane >> 4;
  const int aoff = l15 * 64 + ((d ^ ((l15 >> 1) & 3)) << 4);
  int baddr[8][3];
  bool ok0[8], ok2[8];
#pragma unroll
  for (int n = 0; n < 8; ++n) {
    const int p_out = wn * 128 + n * 16 + l15;   // 0..511
    const int r_out = p_out >> 5, c_out = p_out & 31;
    ok0[n] = (c_out >= 1);
    ok2[n] = (c_out <= 30);
#pragma unroll
    for (int dx = 0; dx < 3; ++dx) {
      const int c = c_out + dx - 1;
      const int cs = ((unsigned)c < 32u) ? c : c_out;   // safe fallback col
      const int row = r_out * 32 + cs;                  // +dy via +2048 (inv.)
      baddr[n][dx] = row * 64 + ((d ^ ((row >> 1) & 3)) << 4);
    }
  }

  // ---- W staging: single linear pointer into pre-arranged wb2 ----
  const unsigned short* wp = wb2 + (size_t)ct * 331776 + lane * 8;
#define WSTAGE(wo)                                                  \
  do {                                                              \
    gld16(wp + wv * 512,          lds + (wo) + wv * 1024);          \
    gld16(wp + wv * 512 + 2048,   lds + (wo) + wv * 1024 + 4096);   \
    gld16(wp + wv * 512 + 4096,   lds + (wo) + wv * 1024 + 8192);   \
    gld16(wp + wv * 512 + 6144,   lds + (wo) + wv * 1024 + 12288);  \
    if (wv < 2)                                                     \
      gld16(wp + wv * 512 + 8192, lds + (wo) + wv * 1024 + 16384);  \
    wp += 9216;                                                     \
  } while (0)

  // ---- IN staging: 36 slabs/chunk; step dy stages slabs dy*12 + wv + 4k ----
  const unsigned short* ip[9];
  int istep[9];
#pragma unroll
  for (int dy2 = 0; dy2 < 3; ++dy2) {
#pragma unroll
    for (int k = 0; k < 3; ++k) {
      const int j = dy2 * 3 + k;
      const int s = dy2 * 12 + wv + 4 * k;       // 0..35
      const int pix = s * 16 + (lane >> 2);      // 0..575
      const int prow = pix >> 5, pcol = pix & 31;
      const int h = h0 - 1 + prow;               // 18-row window
      const int dd = (lane & 3) ^ ((pix >> 1) & 3);
      if (h >= 0 && h < 32) {
        ip[j] = fea + ((size_t)((b * 32 + h) * 32 + pcol) * 384 + dd * 8);
        istep[j] = 32;
      } else {
        ip[j] = zpg + lane * 8;                  // stage zeros (h-edge)
        istep[j] = 0;
      }
    }
  }

  f32x4 acc[6][8] = {};
  const short8 z8 = {0, 0, 0, 0, 0, 0, 0, 0};
  short8 afA[6], bfA[8], afB[6], bfB[8];

#define LOADAF(dst, base, dxc)                                          \
  do {                                                                  \
    _Pragma("unroll") for (int m = 0; m < 6; ++m)                       \
      dst[m] = *reinterpret_cast<const short8*>(                        \
          (base) + (dxc) * 6144 + m * 1024 + aoff);                     \
  } while (0)

#define LOADBF(dst, base, dxc, dyc, M0, M2)                             \
  do {                                                                  \
    _Pragma("unroll") for (int n = 0; n < 8; ++n) {                     \
      short8 v = *reinterpret_cast<const short8*>(                      \
          (base) + baddr[n][dxc] + (dyc) * 2048);                       \
      if (M0) v = ok0[n] ? v : z8;                                      \
      if (M2) v = ok2[n] ? v : z8;                                      \
      dst[n] = v;                                                       \
    }                                                                   \
  } while (0)

#define MFMAB(af, bf)                                                   \
  do {                                                                  \
    _Pragma("unroll") for (int m = 0; m < 6; ++m)                       \
      _Pragma("unroll") for (int n = 0; n < 8; ++n)                     \
        acc[m][n] = __builtin_amdgcn_mfma_f32_16x16x32_bf16(            \
            af[m], bf[n], acc[m][n], 0, 0, 0);                          \
  } while (0)

  // STEP: entry fragment set Ea/Eb; other set Oa/Ob. dy_ compile-time.
#define STEP(cc_, dy_, Ea, Eb, Oa, Ob)                                  \
  do {                                                                  \
    const unsigned char* wbase = lds + (dy_) * 18432;                   \
    const unsigned char* wnext = lds + (((dy_) + 1) % 3) * 18432;       \
    const unsigned char* ibase = lds + 55296 + ((cc_) & 1) * 36864;     \
    if ((cc_) < 11 || (dy_) == 0) WSTAGE((((dy_) + 2) % 3) * 18432);    \
    if ((cc_) < 11) {                                                   \
      const int io = 55296 + (((cc_) + 1) & 1) * 36864;                 \
      const int s0 = (dy_) * 12 + wv;                                   \
      _Pragma("unroll") for (int k = 0; k < 3; ++k) {                   \
        const int j = (dy_) * 3 + k;                                    \
        gld16(ip[j], lds + io + (s0 + 4 * k) * 1024);                   \
        ip[j] += istep[j];                                              \
      }                                                                 \
    }                                                                   \
    /* dx=0: use E, load O <- (wbase,dx=1),(ibase,dx=1) */              \
    LOADAF(Oa, wbase, 1);                                               \
    LOADBF(Ob, ibase, 1, (dy_), 0, 0);                                  \
    MFMAB(Ea, Eb);                                                      \
    /* dx=1: use O, load E <- (wbase,dx=2),(ibase,dx=2,ok2) */          \
    LOADAF(Ea, wbase, 2);                                               \
    LOADBF(Eb, ibase, 2, (dy_), 0, 1);                                  \
    MFMAB(Oa, Ob);                                                      \
    /* dx=2: use E, load O <- next step dx=0 (af always; bf if dy<2) */ \
    if ((cc_) * 3 + (dy_) < 35) {                                       \
      LOADAF(Oa, wnext, 0);                                             \
      if ((dy_) < 2) LOADBF(Ob, ibase, 0, (dy_) + 1, 1, 0);             \
    }                                                                   \
    MFMAB(Ea, Eb);                                                      \
    __syncthreads();                                                    \
    if ((dy_) == 2 && (cc_) < 11) {  /* fresh bf from new chunk */      \
      const unsigned char* ib2 = lds + 55296 + (((cc_) + 1) & 1) * 36864; \
      LOADBF(Ob, ib2, 0, 0, 1, 0);                                      \
    }                                                                   \
  } while (0)

  // ---- prologue: W[0]->buf0, W[1]->buf1; IN chunk 0 -> ibuf0 ----
  WSTAGE(0);
  WSTAGE(18432);
#pragma unroll
  for (int j = 0; j < 9; ++j) {
    const int dy2 = j / 3, k = j - dy2 * 3;
    const int s = dy2 * 12 + wv + 4 * k;
    gld16(ip[j], lds + 55296 + s * 1024);
    ip[j] += istep[j];
  }
  __syncthreads();
  // entry set A for step 0 (buf0, ibuf0, dx=0)
  LOADAF(afA, lds, 0);
  LOADBF(bfA, lds + 55296, 0, 0, 1, 0);

  for (int cc = 0; cc < 12; cc += 2) {
    STEP(cc,     0, afA, bfA, afB, bfB);
    STEP(cc,     1, afB, bfB, afA, bfA);
    STEP(cc,     2, afA, bfA, afB, bfB);
    STEP(cc + 1, 0, afB, bfB, afA, bfA);
    STEP(cc + 1, 1, afA, bfA, afB, bfB);
    STEP(cc + 1, 2, afB, bfB, afA, bfA);
  }
#undef WSTAGE
#undef STEP

  // ---- BN partial stats (no stores yet) ----
#pragma unroll
  for (int m = 0; m < 6; ++m) {
#pragma unroll
    for (int r = 0; r < 4; ++r) {
      const int co = m * 16 + d * 4 + r;     // within co tile
      float s = 0.f, q = 0.f;
#pragma unroll
      for (int n = 0; n < 8; ++n) {
        const float v = acc[m][n][r];
        s += v; q += v * v;
      }
#pragma unroll
      for (int off = 1; off < 16; off <<= 1) {
        s += __shfl_xor(s, off, 64);
        q += __shfl_xor(q, off, 64);
      }
      if (l15 == 0) {
        atomicAdd(&bn_sum[co0 + co], s);
        atomicAdd(&bn_sq[co0 + co], q);
      }
    }
  }

  // ---- group barrier: 64 blocks of this ct ----
  __threadfence();
  __syncthreads();
  if (tid == 0) atomicAdd(&ctr[ct], 1);
  if (tid == 0) {
    while (__hip_atomic_load(&ctr[ct], __ATOMIC_ACQUIRE,
                             __HIP_MEMORY_SCOPE_AGENT) < 64)
      __builtin_amdgcn_s_sleep(8);
  }
  __syncthreads();

  // ---- build per-co (rs, b') in LDS; normalize acc; store ----
  float* ls_rs = reinterpret_cast<float*>(lds);
  float* ls_bb = reinterpret_cast<float*>(lds + 512);
  if (tid < 96) {
    const int co = co0 + tid;
    const float sv = __hip_atomic_load(&bn_sum[co], __ATOMIC_RELAXED,
                                       __HIP_MEMORY_SCOPE_AGENT);
    const float qv = __hip_atomic_load(&bn_sq[co], __ATOMIC_RELAXED,
                                       __HIP_MEMORY_SCOPE_AGENT);
    const float inv = 1.0f / 32768.0f;
    const float mu = sv * inv;
    const float var = fmaxf(qv * inv - mu * mu, 0.0f);
    const float rs = rsqrtf(var + 1e-5f) * gamma[co];
    ls_rs[tid] = rs;
    ls_bb[tid] = beta[co] - mu * rs;
  }
  __syncthreads();

  const size_t ob = (((size_t)b * 384 + co0) << 10) + h0 * 32;
#pragma unroll
  for (int m = 0; m < 6; ++m) {
#pragma unroll
    for (int r = 0; r < 4; ++r) {
      const int co = m * 16 + d * 4 + r;
      const float rs = ls_rs[co], bb = ls_bb[co];
#pragma unroll
      for (int n = 0; n < 8; ++n) {
        const int p = wn * 128 + n * 16 + l15;  // 0..511 within 16-row strip
        out[ob + ((size_t)co << 10) + p] = acc[m][n][r] * rs + bb;
      }
    }
  }
}

extern "C" void kernel_launch(void* const* d_in, const int* in_sizes, int n_in,
                              void* d_out, int out_size, void* d_ws, size_t ws_size,
                              hipStream_t stream) {
  const float* x     = (const float*)d_in[0];
  const float* pmp   = (const float*)d_in[1];
  const float* psp   = (const float*)d_in[2];
  const float* pmn   = (const float*)d_in[3];
  const float* psn   = (const float*)d_in[4];
  const float* cw    = (const float*)d_in[5];
  const float* convw = (const float*)d_in[6];
  const float* gamma = (const float*)d_in[7];
  const float* beta  = (const float*)d_in[8];
  const int*   label = (const int*)d_in[9];
  float* out = (float*)d_out;
  char* ws = (char*)d_ws;

  // ws layout (~28 MB total)
  unsigned short* fea = (unsigned short*)(ws);                 // 25165824 B
  unsigned short* wb2 = (unsigned short*)(ws + 25165824);      //  2654208 B
  float* sums  = (float*)(ws + 27820032);                      //    49152 B
  float* sumsq = (float*)(ws + 27869184);                      //    49152 B
  float* Ac    = (float*)(ws + 27918336);                      //    49152 B
  float* Bc    = (float*)(ws + 27967488);                      //    49152 B
  float* bn    = (float*)(ws + 28016640);                      //     3072 B
  float* zp    = (float*)(ws + 28019712);                      //     4096 B
  int*   ctr   = (int*)(ws + 28023808);                        //       16 B

  k_stats<<<dim3(12288), dim3(256), 0, stream>>>(x, sums, sumsq, bn, ctr, zp);
  k_coef<<<dim3(32), dim3(384), 0, stream>>>(pmp, psp, pmn, psn, cw, label,
                                             sums, sumsq, Ac, Bc);
  k_fea<<<dim3(128, 6), dim3(256), 0, stream>>>(x, Ac, Bc, fea);
  k_wcvt<<<dim3(648), dim3(256), 0, stream>>>(convw, wb2);
  k_conv<<<dim3(64, 4), dim3(256), 0, stream>>>(fea, wb2, (const unsigned short*)zp,
                                                out, bn, bn + 384, gamma, beta, ctr);
}

// Round 16
// 154.172 us; speedup vs baseline: 1.1071x; 1.1071x over previous
//
#include <hip/hip_runtime.h>
#include <stdint.h>

using f32x4  = __attribute__((ext_vector_type(4))) float;
using short8 = __attribute__((ext_vector_type(8))) short;

#define DEVI static __device__ __forceinline__

// float -> bf16 round-to-nearest-even
DEVI unsigned short f2bf(float f) {
  unsigned u = __float_as_uint(f);
  u += 0x7FFFu + ((u >> 16) & 1u);
  return (unsigned short)(u >> 16);
}

// async global->LDS, 16B per lane. LDS dest is wave-uniform base; HW writes
// base + lane*16. Global src is per-lane.
DEVI void gld16(const void* g, void* l) {
  __builtin_amdgcn_global_load_lds(
      reinterpret_cast<const __attribute__((address_space(1))) unsigned int*>(
          reinterpret_cast<uintptr_t>(g)),
      reinterpret_cast<__attribute__((address_space(3))) unsigned int*>(
          reinterpret_cast<uintptr_t>(l)),
      16, 0, 0);
}

// ---------------- K1: per-(b,c) sum/sumsq of x; block 0 zeroes bn/ctr/zp ----
__global__ __launch_bounds__(256) void k_stats(const float* __restrict__ x,
                                               float* __restrict__ sums,
                                               float* __restrict__ sumsq,
                                               float* __restrict__ bn,
                                               int* __restrict__ ctr,
                                               float* __restrict__ zp) {
  const int bc = blockIdx.x;  // 0..12287
  if (bc == 0) {              // zero bn stats/ctr/zero-page before k_conv
    const int t = threadIdx.x;
    for (int i = t; i < 768; i += 256) bn[i] = 0.0f;
    for (int i = t; i < 1024; i += 256) zp[i] = 0.0f;
    if (t < 4) ctr[t] = 0;
  }
  const float4 v =
      reinterpret_cast<const float4*>(x + (size_t)bc * 1024)[threadIdx.x];
  float s = v.x + v.y + v.z + v.w;
  float q = v.x * v.x + v.y * v.y + v.z * v.z + v.w * v.w;
#pragma unroll
  for (int off = 1; off < 64; off <<= 1) {
    s += __shfl_xor(s, off, 64);
    q += __shfl_xor(q, off, 64);
  }
  __shared__ float ls[4], lq[4];
  const int wv = threadIdx.x >> 6;
  if ((threadIdx.x & 63) == 0) { ls[wv] = s; lq[wv] = q; }
  __syncthreads();
  if (threadIdx.x == 0) {
    sums[bc]  = ls[0] + ls[1] + ls[2] + ls[3];
    sumsq[bc] = lq[0] + lq[1] + lq[2] + lq[3];
  }
}

// ---------------- K2: MERGED prep kernel (384 threads) ----------------
// blocks 0..431:  conv_w (OIHW f32) -> wb2 pre-staged order (165888 = 432*384)
// blocks 432..463: CSA coefficient fold (32 batches x 384 channels)
// wb2 = [ct(4)][step(36)=cc*3+dy][slab(18)][lane(64)][8 bf16]; slab row
// r = slab*16+(lane>>2) = dxl*96+co_l; tap = dy*3+dxl; grp g=lane&3 holds
// data grp dd = g ^ ((co_l>>1)&3); ci = cc*32 + dd*8 + u.
__global__ __launch_bounds__(384) void k_prep(
    const float* __restrict__ w, unsigned short* __restrict__ wb2,
    const float* __restrict__ pmp, const float* __restrict__ psp,
    const float* __restrict__ pmn, const float* __restrict__ psn,
    const float* __restrict__ cw, const int* __restrict__ label,
    const float* __restrict__ sums, const float* __restrict__ sumsq,
    float* __restrict__ Ac, float* __restrict__ Bc) {
  if (blockIdx.x < 432) {
    // ---- weight convert/pre-stage ----
    const int g = blockIdx.x * 384 + threadIdx.x;  // 0..165887
    const int ct = g / 41472;
    const int r1 = g - ct * 41472;
    const int step = r1 / 1152;
    const int r2 = r1 - step * 1152;
    const int slab = r2 >> 6;
    const int lane = r2 & 63;
    const int cc = step / 3, dy = step - cc * 3;
    const int r = slab * 16 + (lane >> 2);         // 0..287
    const int dxl = r / 96, co_l = r - dxl * 96;
    const int dd = (lane & 3) ^ ((co_l >> 1) & 3);
    const int tap = dy * 3 + dxl;
    const int co = ct * 96 + co_l;
    const int cib = cc * 32 + dd * 8;
    union { unsigned short us[8]; uint4 v4; } pk;
#pragma unroll
    for (int u = 0; u < 8; ++u)
      pk.us[u] = f2bf(w[(size_t)(co * 384 + cib + u) * 9 + tap]);
    *reinterpret_cast<uint4*>(wb2 + (size_t)g * 8) = pk.v4;
    return;
  }
  // ---- CSA coefficient fold ----
  const int b = blockIdx.x - 432;  // 0..31
  const int c = threadIdx.x;       // 0..383
  __shared__ float w0[64], w1[64];
  if (threadIdx.x < 64) w0[threadIdx.x] = cw[b * 64 + threadIdx.x];
  else if (threadIdx.x < 128) w1[threadIdx.x - 64] = cw[2048 + b * 64 + (threadIdx.x - 64)];
  __syncthreads();
  const bool sel = (label[b] == 0);
  const float* m1t = (sel ? pmp : pmn);           // layer 0 tables [K=64][C=384]
  const float* s1t = (sel ? psp : psn);
  const float* m2t = m1t + 64 * 384;              // layer 1
  const float* s2t = s1t + 64 * 384;
  float m1 = 0.f, s1 = 0.f, m2 = 0.f, s2 = 0.f;
  for (int k = 0; k < 64; ++k) {
    const float a0 = w0[k], a1 = w1[k];
    m1 += a0 * m1t[k * 384 + c];
    s1 += a0 * s1t[k * 384 + c];
    m2 += a1 * m2t[k * 384 + c];
    s2 += a1 * s2t[k * 384 + c];
  }
  const int bc = b * 384 + c;
  const float sum = sums[bc], sq = sumsq[bc];
  const float mean = sum * (1.0f / 1024.0f);
  float var = (sq - sum * mean) * (1.0f / 1023.0f);  // ddof=1
  var = fmaxf(var, 0.0f);
  const float sd1 = sqrtf(var + 1e-5f);
  const float a1c = 1.0f + s1 / sd1;
  const float b1c = m1 - mean * (s1 / sd1);
  const float mean1 = a1c * mean + b1c;      // exact mean of affine fea1
  const float var1  = a1c * a1c * var;       // exact ddof=1 var of affine fea1
  const float sd2 = sqrtf(var1 + 1e-5f);
  const float t2 = 1.0f + s2 / sd2;
  Ac[bc] = a1c * t2;
  Bc[bc] = b1c * t2 + m2 - mean1 * (s2 / sd2);
}

// ---------------- K3: fea2 NHWC bf16 = A*x + B (LDS transpose for writes) ----
// grid (128,6): block = 256 pixels x 64 channels
__global__ __launch_bounds__(256) void k_fea(const float* __restrict__ x,
                                             const float* __restrict__ Ac,
                                             const float* __restrict__ Bc,
                                             unsigned short* __restrict__ fea) {
  __shared__ unsigned short tb[256][68];   // +4 pad: bank-conflict-free
  const int t = threadIdx.x;
  const int g0 = blockIdx.x << 8;          // pixel base
  const int b = g0 >> 10;                  // uniform per block
  const int c0 = blockIdx.y * 64;
  const float* xb = x + (((size_t)b * 384) << 10) + (g0 & 1023) + t;
  const float* Ab = Ac + b * 384 + c0;
  const float* Bb = Bc + b * 384 + c0;
#pragma unroll 1
  for (int u8 = 0; u8 < 64; u8 += 8) {
    union { unsigned short us[8]; uint4 v; } pk;
#pragma unroll
    for (int u = 0; u < 8; ++u) {
      const int c = u8 + u;
      pk.us[u] = f2bf(Ab[c] * xb[(size_t)(c0 + c) << 10] + Bb[c]);
    }
    *reinterpret_cast<uint4*>(&tb[t][u8]) = pk.v;
  }
  __syncthreads();
  const int j = t & 7;
#pragma unroll
  for (int rep = 0; rep < 8; ++rep) {
    const int p = rep * 32 + (t >> 3);
    const uint4 v = *reinterpret_cast<const uint4*>(&tb[p][j * 8]);
    *reinterpret_cast<uint4*>(fea + (size_t)(g0 + p) * 384 + c0 + j * 8) = v;
  }
}

// ---------------- K5: implicit-GEMM conv + BN stats + FUSED BN finalize ----
// R14 loop (best verified). After BN atomics, per-ct group barrier (64
// co-resident blocks) replaces the 100MB bnfin pass: stats agent-scope,
// (rs,b') in LDS, acc normalized in registers, single store.
// Deadlock-safe: grid = 256 blocks = 1/CU, all resident (LDS 129KB/block).
__global__ __launch_bounds__(256, 1) void k_conv(
    const unsigned short* __restrict__ fea, const unsigned short* __restrict__ wb2,
    const unsigned short* __restrict__ zpg, float* __restrict__ out,
    float* __restrict__ bn_sum, float* __restrict__ bn_sq,
    const float* __restrict__ gamma, const float* __restrict__ beta,
    int* __restrict__ ctr) {
  __shared__ __align__(16) unsigned char lds[129024];
  const int tid = threadIdx.x;
  const int lane = tid & 63, wv = tid >> 6;
  const int pt = blockIdx.x;      // 0..63
  const int ct = blockIdx.y;      // 0..3
  const int b = pt >> 1, h0 = (pt & 1) * 16;
  const int co0 = ct * 96;
  const int wn = wv;              // pixel quarter (128 px = 4 rows each)

  // ---- hoisted LDS read addresses ----
  const int l15 = lane & 15, d = lane >> 4;
  const int aoff = l15 * 64 + ((d ^ ((l15 >> 1) & 3)) << 4);
  int baddr[8][3];
  bool ok0[8], ok2[8];
#pragma unroll
  for (int n = 0; n < 8; ++n) {
    const int p_out = wn * 128 + n * 16 + l15;   // 0..511
    const int r_out = p_out >> 5, c_out = p_out & 31;
    ok0[n] = (c_out >= 1);
    ok2[n] = (c_out <= 30);
#pragma unroll
    for (int dx = 0; dx < 3; ++dx) {
      const int c = c_out + dx - 1;
      const int cs = ((unsigned)c < 32u) ? c : c_out;   // safe fallback col
      const int row = r_out * 32 + cs;                  // +dy via +2048 (inv.)
      baddr[n][dx] = row * 64 + ((d ^ ((row >> 1) & 3)) << 4);
    }
  }

  // ---- W staging: single linear pointer into pre-arranged wb2 ----
  const unsigned short* wp = wb2 + (size_t)ct * 331776 + lane * 8;
#define WSTAGE(wo)                                                  \
  do {                                                              \
    gld16(wp + wv * 512,          lds + (wo) + wv * 1024);          \
    gld16(wp + wv * 512 + 2048,   lds + (wo) + wv * 1024 + 4096);   \
    gld16(wp + wv * 512 + 4096,   lds + (wo) + wv * 1024 + 8192);   \
    gld16(wp + wv * 512 + 6144,   lds + (wo) + wv * 1024 + 12288);  \
    if (wv < 2)                                                     \
      gld16(wp + wv * 512 + 8192, lds + (wo) + wv * 1024 + 16384);  \
    wp += 9216;                                                     \
  } while (0)

  // ---- IN staging: 36 slabs/chunk; step dy stages slabs dy*12 + wv + 4k ----
  const unsigned short* ip[9];
  int istep[9];
#pragma unroll
  for (int dy2 = 0; dy2 < 3; ++dy2) {
#pragma unroll
    for (int k = 0; k < 3; ++k) {
      const int j = dy2 * 3 + k;
      const int s = dy2 * 12 + wv + 4 * k;       // 0..35
      const int pix = s * 16 + (lane >> 2);      // 0..575
      const int prow = pix >> 5, pcol = pix & 31;
      const int h = h0 - 1 + prow;               // 18-row window
      const int dd = (lane & 3) ^ ((pix >> 1) & 3);
      if (h >= 0 && h < 32) {
        ip[j] = fea + ((size_t)((b * 32 + h) * 32 + pcol) * 384 + dd * 8);
        istep[j] = 32;
      } else {
        ip[j] = zpg + lane * 8;                  // stage zeros (h-edge)
        istep[j] = 0;
      }
    }
  }

  f32x4 acc[6][8] = {};
  const short8 z8 = {0, 0, 0, 0, 0, 0, 0, 0};
  short8 pf_af[6], pf_bf[8];

  // ---- prologue: W[0]->buf0, W[1]->buf1; IN chunk 0 -> ibuf0 ----
  WSTAGE(0);
  WSTAGE(18432);
#pragma unroll
  for (int j = 0; j < 9; ++j) {
    const int dy2 = j / 3, k = j - dy2 * 3;
    const int s = dy2 * 12 + wv + 4 * k;
    gld16(ip[j], lds + 55296 + s * 1024);
    ip[j] += istep[j];
  }
  __syncthreads();
  // prefetch af for step 0 (buf0, dx=0)
#pragma unroll
  for (int m = 0; m < 6; ++m)
    pf_af[m] = *reinterpret_cast<const short8*>(lds + m * 1024 + aoff);

  for (int cc = 0; cc < 12; ++cc) {
#pragma unroll
    for (int dy = 0; dy < 3; ++dy) {
      const int st = cc * 3 + dy;
      // compile-time buffer selects: st % 3 == dy
      const unsigned char* wbase = lds + dy * 18432;
      const unsigned char* wnext = lds + ((dy + 1) % 3) * 18432;
      const unsigned char* ibase = lds + 55296 + (cc & 1) * 36864;
      // stage W(st+2) into buf (dy+2)%3
      if (cc < 11 || dy == 0) WSTAGE(((dy + 2) % 3) * 18432);
      // stage IN(chunk cc+1), dy-th third, into the other IN buffer
      if (cc < 11) {
        const int io = 55296 + ((cc + 1) & 1) * 36864;
        const int s0 = dy * 12 + wv;
#pragma unroll
        for (int k = 0; k < 3; ++k) {
          const int j = dy * 3 + k;
          gld16(ip[j], lds + io + (s0 + 4 * k) * 1024);
          ip[j] += istep[j];
        }
      }
      // ---- compute 3 dx taps of (cc, dy) ----
#pragma unroll
      for (int dx = 0; dx < 3; ++dx) {
        short8 af[6], bf[8];
        if (dx == 0) {
#pragma unroll
          for (int m = 0; m < 6; ++m) af[m] = pf_af[m];
          if (dy == 0) {                         // bf fresh at chunk entry
#pragma unroll
            for (int n = 0; n < 8; ++n) {
              short8 v = *reinterpret_cast<const short8*>(ibase + baddr[n][0]);
              bf[n] = ok0[n] ? v : z8;
            }
          } else {
#pragma unroll
            for (int n = 0; n < 8; ++n) bf[n] = pf_bf[n];
          }
        } else {
#pragma unroll
          for (int m = 0; m < 6; ++m)
            af[m] = *reinterpret_cast<const short8*>(
                wbase + dx * 6144 + m * 1024 + aoff);
#pragma unroll
          for (int n = 0; n < 8; ++n) {
            short8 v = *reinterpret_cast<const short8*>(
                ibase + baddr[n][dx] + dy * 2048);
            if (dx == 2) v = ok2[n] ? v : z8;
            bf[n] = v;
          }
        }
#pragma unroll
        for (int m = 0; m < 6; ++m)
#pragma unroll
          for (int n = 0; n < 8; ++n)
            acc[m][n] = __builtin_amdgcn_mfma_f32_16x16x32_bf16(
                af[m], bf[n], acc[m][n], 0, 0, 0);
      }
      // ---- prefetch step st+1's dx=0 fragments (W[st+1] resident) ----
      if (st < 35) {
#pragma unroll
        for (int m = 0; m < 6; ++m)
          pf_af[m] = *reinterpret_cast<const short8*>(wnext + m * 1024 + aoff);
        if (dy < 2) {                            // st+1 in same IN chunk
#pragma unroll
          for (int n = 0; n < 8; ++n) {
            short8 v = *reinterpret_cast<const short8*>(
                ibase + baddr[n][0] + (dy + 1) * 2048);
            pf_bf[n] = ok0[n] ? v : z8;
          }
        }
      }
      __syncthreads();
    }
  }
#undef WSTAGE

  // ---- BN partial stats (no stores yet) ----
#pragma unroll
  for (int m = 0; m < 6; ++m) {
#pragma unroll
    for (int r = 0; r < 4; ++r) {
      const int co = m * 16 + d * 4 + r;     // within co tile
      float s = 0.f, q = 0.f;
#pragma unroll
      for (int n = 0; n < 8; ++n) {
        const float v = acc[m][n][r];
        s += v; q += v * v;
      }
#pragma unroll
      for (int off = 1; off < 16; off <<= 1) {
        s += __shfl_xor(s, off, 64);
        q += __shfl_xor(q, off, 64);
      }
      if (l15 == 0) {
        atomicAdd(&bn_sum[co0 + co], s);
        atomicAdd(&bn_sq[co0 + co], q);
      }
    }
  }

  // prefetch gamma/beta for this thread's co range before the spin
  float gpref = 0.f, bpref = 0.f;
  if (tid < 96) { gpref = gamma[co0 + tid]; bpref = beta[co0 + tid]; }

  // ---- group barrier: 64 blocks of this ct ----
  __threadfence();
  __syncthreads();
  if (tid == 0) atomicAdd(&ctr[ct], 1);
  if (tid == 0) {
    while (__hip_atomic_load(&ctr[ct], __ATOMIC_ACQUIRE,
                             __HIP_MEMORY_SCOPE_AGENT) < 64)
      __builtin_amdgcn_s_sleep(2);
  }
  __syncthreads();

  // ---- build per-co (rs, b') in LDS; normalize acc; store ----
  float* ls_rs = reinterpret_cast<float*>(lds);
  float* ls_bb = reinterpret_cast<float*>(lds + 512);
  if (tid < 96) {
    const int co = co0 + tid;
    const float sv = __hip_atomic_load(&bn_sum[co], __ATOMIC_RELAXED,
                                       __HIP_MEMORY_SCOPE_AGENT);
    const float qv = __hip_atomic_load(&bn_sq[co], __ATOMIC_RELAXED,
                                       __HIP_MEMORY_SCOPE_AGENT);
    const float inv = 1.0f / 32768.0f;
    const float mu = sv * inv;
    const float var = fmaxf(qv * inv - mu * mu, 0.0f);
    const float rs = rsqrtf(var + 1e-5f) * gpref;
    ls_rs[tid] = rs;
    ls_bb[tid] = bpref - mu * rs;
  }
  __syncthreads();

  const size_t ob = (((size_t)b * 384 + co0) << 10) + h0 * 32;
#pragma unroll
  for (int m = 0; m < 6; ++m) {
#pragma unroll
    for (int r = 0; r < 4; ++r) {
      const int co = m * 16 + d * 4 + r;
      const float rs = ls_rs[co], bb = ls_bb[co];
#pragma unroll
      for (int n = 0; n < 8; ++n) {
        const int p = wn * 128 + n * 16 + l15;  // 0..511 within 16-row strip
        out[ob + ((size_t)co << 10) + p] = acc[m][n][r] * rs + bb;
      }
    }
  }
}

extern "C" void kernel_launch(void* const* d_in, const int* in_sizes, int n_in,
                              void* d_out, int out_size, void* d_ws, size_t ws_size,
                              hipStream_t stream) {
  const float* x     = (const float*)d_in[0];
  const float* pmp   = (const float*)d_in[1];
  const float* psp   = (const float*)d_in[2];
  const float* pmn   = (const float*)d_in[3];
  const float* psn   = (const float*)d_in[4];
  const float* cw    = (const float*)d_in[5];
  const float* convw = (const float*)d_in[6];
  const float* gamma = (const float*)d_in[7];
  const float* beta  = (const float*)d_in[8];
  const int*   label = (const int*)d_in[9];
  float* out = (float*)d_out;
  char* ws = (char*)d_ws;

  // ws layout (~28 MB total)
  unsigned short* fea = (unsigned short*)(ws);                 // 25165824 B
  unsigned short* wb2 = (unsigned short*)(ws + 25165824);      //  2654208 B
  float* sums  = (float*)(ws + 27820032);                      //    49152 B
  float* sumsq = (float*)(ws + 27869184);                      //    49152 B
  float* Ac    = (float*)(ws + 27918336);                      //    49152 B
  float* Bc    = (float*)(ws + 27967488);                      //    49152 B
  float* bn    = (float*)(ws + 28016640);                      //     3072 B
  float* zp    = (float*)(ws + 28019712);                      //     4096 B
  int*   ctr   = (int*)(ws + 28023808);                        //       16 B

  k_stats<<<dim3(12288), dim3(256), 0, stream>>>(x, sums, sumsq, bn, ctr, zp);
  k_prep<<<dim3(464), dim3(384), 0, stream>>>(convw, wb2, pmp, psp, pmn, psn,
                                              cw, label, sums, sumsq, Ac, Bc);
  k_fea<<<dim3(128, 6), dim3(256), 0, stream>>>(x, Ac, Bc, fea);
  k_conv<<<dim3(64, 4), dim3(256), 0, stream>>>(fea, wb2, (const unsigned short*)zp,
                                                out, bn, bn + 384, gamma, beta, ctr);
}

// Round 17
// 151.227 us; speedup vs baseline: 1.1286x; 1.0195x over previous
//
#include <hip/hip_runtime.h>
#include <stdint.h>

using f32x4  = __attribute__((ext_vector_type(4))) float;
using short8 = __attribute__((ext_vector_type(8))) short;

#define DEVI static __device__ __forceinline__

// float -> bf16 round-to-nearest-even
DEVI unsigned short f2bf(float f) {
  unsigned u = __float_as_uint(f);
  u += 0x7FFFu + ((u >> 16) & 1u);
  return (unsigned short)(u >> 16);
}

// async global->LDS, 16B per lane. LDS dest is wave-uniform base; HW writes
// base + lane*16. Global src is per-lane.
DEVI void gld16(const void* g, void* l) {
  __builtin_amdgcn_global_load_lds(
      reinterpret_cast<const __attribute__((address_space(1))) unsigned int*>(
          reinterpret_cast<uintptr_t>(g)),
      reinterpret_cast<__attribute__((address_space(3))) unsigned int*>(
          reinterpret_cast<uintptr_t>(l)),
      16, 0, 0);
}

// ---------------- K1: stats (12288 blocks) + weight pre-stage (648 blocks) ----
// Blocks 0..12287: per-(b,c) sum/sumsq of x; block 0 zeroes bn/ctr/zp.
// Blocks 12288..12935: conv_w (OIHW f32) -> wb2 pre-staged order.
// wb2 = [ct(4)][step(36)=cc*3+dy][slab(18)][lane(64)][8 bf16]; slab row
// r = slab*16+(lane>>2) = dxl*96+co_l; tap = dy*3+dxl; grp g=lane&3 holds
// data grp dd = g ^ ((co_l>>1)&3); ci = cc*32 + dd*8 + u.
__global__ __launch_bounds__(256) void k_stats(const float* __restrict__ x,
                                               float* __restrict__ sums,
                                               float* __restrict__ sumsq,
                                               float* __restrict__ bn,
                                               int* __restrict__ ctr,
                                               float* __restrict__ zp,
                                               const float* __restrict__ w,
                                               unsigned short* __restrict__ wb2) {
  const int bid = blockIdx.x;
  if (bid >= 12288) {
    // ---- weight convert/pre-stage ----
    const int g = (bid - 12288) * 256 + threadIdx.x;  // 0..165887
    const int ct = g / 41472;
    const int r1 = g - ct * 41472;
    const int step = r1 / 1152;
    const int r2 = r1 - step * 1152;
    const int slab = r2 >> 6;
    const int lane = r2 & 63;
    const int cc = step / 3, dy = step - cc * 3;
    const int r = slab * 16 + (lane >> 2);         // 0..287
    const int dxl = r / 96, co_l = r - dxl * 96;
    const int dd = (lane & 3) ^ ((co_l >> 1) & 3);
    const int tap = dy * 3 + dxl;
    const int co = ct * 96 + co_l;
    const int cib = cc * 32 + dd * 8;
    union { unsigned short us[8]; uint4 v4; } pk;
#pragma unroll
    for (int u = 0; u < 8; ++u)
      pk.us[u] = f2bf(w[(size_t)(co * 384 + cib + u) * 9 + tap]);
    *reinterpret_cast<uint4*>(wb2 + (size_t)g * 8) = pk.v4;
    return;
  }
  const int bc = bid;  // 0..12287
  if (bc == 0) {       // zero bn stats/ctr/zero-page before k_conv
    const int t = threadIdx.x;
    for (int i = t; i < 768; i += 256) bn[i] = 0.0f;
    for (int i = t; i < 1024; i += 256) zp[i] = 0.0f;
    if (t < 4) ctr[t] = 0;
  }
  const float4 v =
      reinterpret_cast<const float4*>(x + (size_t)bc * 1024)[threadIdx.x];
  float s = v.x + v.y + v.z + v.w;
  float q = v.x * v.x + v.y * v.y + v.z * v.z + v.w * v.w;
#pragma unroll
  for (int off = 1; off < 64; off <<= 1) {
    s += __shfl_xor(s, off, 64);
    q += __shfl_xor(q, off, 64);
  }
  __shared__ float ls[4], lq[4];
  const int wv = threadIdx.x >> 6;
  if ((threadIdx.x & 63) == 0) { ls[wv] = s; lq[wv] = q; }
  __syncthreads();
  if (threadIdx.x == 0) {
    sums[bc]  = ls[0] + ls[1] + ls[2] + ls[3];
    sumsq[bc] = lq[0] + lq[1] + lq[2] + lq[3];
  }
}

// ---------------- K3: CSA coef fold + fea2 NHWC bf16 = A*x + B ----------------
// grid (128,6): block = 256 pixels x 64 channels. Each block computes the
// CSA-fold coefficients (A,B) for ITS 64 channels in-block (4-wave k-split,
// coalesced table reads, LDS reduce; 4x redundant vs a dedicated kernel but
// tables are L2/L3-resident), then applies fea2 = A*x + B with the verified
// LDS-transpose write path.
__global__ __launch_bounds__(256) void k_fea(
    const float* __restrict__ x, const float* __restrict__ pmp,
    const float* __restrict__ psp, const float* __restrict__ pmn,
    const float* __restrict__ psn, const float* __restrict__ cw,
    const int* __restrict__ label, const float* __restrict__ sums,
    const float* __restrict__ sumsq, unsigned short* __restrict__ fea) {
  __shared__ unsigned short tb[256][68];   // +4 pad: bank-conflict-free
  __shared__ float w01[128];
  __shared__ float part[4][64][4];
  __shared__ float As[64], Bs[64];
  const int t = threadIdx.x;
  const int g0 = blockIdx.x << 8;          // pixel base
  const int b = blockIdx.x >> 2;           // batch (uniform per block)
  const int c0 = blockIdx.y * 64;

  // ---- load combine weights ----
  if (t < 64) w01[t] = cw[b * 64 + t];
  else if (t < 128) w01[t] = cw[2048 + b * 64 + (t - 64)];
  __syncthreads();

  // ---- per-channel coef fold: c = c0 + (t&63), k-quarter = t>>6 ----
  {
    const bool sel = (label[b] == 0);
    const float* m1t = (sel ? pmp : pmn);  // layer 0 tables [K=64][C=384]
    const float* s1t = (sel ? psp : psn);
    const float* m2t = m1t + 64 * 384;     // layer 1
    const float* s2t = s1t + 64 * 384;
    const int cl = t & 63, kq = t >> 6;
    const int c = c0 + cl;
    float m1 = 0.f, s1 = 0.f, m2 = 0.f, s2 = 0.f;
#pragma unroll
    for (int i = 0; i < 16; ++i) {
      const int k = kq * 16 + i;
      const float a0 = w01[k], a1 = w01[64 + k];
      m1 += a0 * m1t[k * 384 + c];
      s1 += a0 * s1t[k * 384 + c];
      m2 += a1 * m2t[k * 384 + c];
      s2 += a1 * s2t[k * 384 + c];
    }
    part[kq][cl][0] = m1; part[kq][cl][1] = s1;
    part[kq][cl][2] = m2; part[kq][cl][3] = s2;
  }
  __syncthreads();
  if (t < 64) {
    const float m1 = part[0][t][0] + part[1][t][0] + part[2][t][0] + part[3][t][0];
    const float s1 = part[0][t][1] + part[1][t][1] + part[2][t][1] + part[3][t][1];
    const float m2 = part[0][t][2] + part[1][t][2] + part[2][t][2] + part[3][t][2];
    const float s2 = part[0][t][3] + part[1][t][3] + part[2][t][3] + part[3][t][3];
    const int bc = b * 384 + c0 + t;
    const float sum = sums[bc], sq = sumsq[bc];
    const float mean = sum * (1.0f / 1024.0f);
    float var = (sq - sum * mean) * (1.0f / 1023.0f);  // ddof=1
    var = fmaxf(var, 0.0f);
    const float sd1 = sqrtf(var + 1e-5f);
    const float a1c = 1.0f + s1 / sd1;
    const float b1c = m1 - mean * (s1 / sd1);
    const float mean1 = a1c * mean + b1c;   // exact mean of affine fea1
    const float var1  = a1c * a1c * var;    // exact ddof=1 var of affine fea1
    const float sd2 = sqrtf(var1 + 1e-5f);
    const float t2 = 1.0f + s2 / sd2;
    As[t] = a1c * t2;
    Bs[t] = b1c * t2 + m2 - mean1 * (s2 / sd2);
  }
  __syncthreads();

  // ---- fea2 = A*x + B, NHWC bf16 via LDS transpose (verified path) ----
  const float* xb = x + (((size_t)b * 384) << 10) + (g0 & 1023) + t;
#pragma unroll 1
  for (int u8 = 0; u8 < 64; u8 += 8) {
    union { unsigned short us[8]; uint4 v; } pk;
#pragma unroll
    for (int u = 0; u < 8; ++u) {
      const int c = u8 + u;
      pk.us[u] = f2bf(As[c] * xb[(size_t)(c0 + c) << 10] + Bs[c]);
    }
    *reinterpret_cast<uint4*>(&tb[t][u8]) = pk.v;
  }
  __syncthreads();
  const int j = t & 7;
#pragma unroll
  for (int rep = 0; rep < 8; ++rep) {
    const int p = rep * 32 + (t >> 3);
    const uint4 v = *reinterpret_cast<const uint4*>(&tb[p][j * 8]);
    *reinterpret_cast<uint4*>(fea + (size_t)(g0 + p) * 384 + c0 + j * 8) = v;
  }
}

// ---------------- K5: implicit-GEMM conv + BN stats + FUSED BN finalize ----
// R14/R16 loop (best verified). After BN atomics, per-ct group barrier (64
// co-resident blocks) replaces the 100MB bnfin pass: stats agent-scope,
// (rs,b') in LDS, acc normalized in registers, single store.
// Deadlock-safe: grid = 256 blocks = 1/CU, all resident (LDS 129KB/block).
__global__ __launch_bounds__(256, 1) void k_conv(
    const unsigned short* __restrict__ fea, const unsigned short* __restrict__ wb2,
    const unsigned short* __restrict__ zpg, float* __restrict__ out,
    float* __restrict__ bn_sum, float* __restrict__ bn_sq,
    const float* __restrict__ gamma, const float* __restrict__ beta,
    int* __restrict__ ctr) {
  __shared__ __align__(16) unsigned char lds[129024];
  const int tid = threadIdx.x;
  const int lane = tid & 63, wv = tid >> 6;
  const int pt = blockIdx.x;      // 0..63
  const int ct = blockIdx.y;      // 0..3
  const int b = pt >> 1, h0 = (pt & 1) * 16;
  const int co0 = ct * 96;
  const int wn = wv;              // pixel quarter (128 px = 4 rows each)

  // ---- hoisted LDS read addresses ----
  const int l15 = lane & 15, d = lane >> 4;
  const int aoff = l15 * 64 + ((d ^ ((l15 >> 1) & 3)) << 4);
  int baddr[8][3];
  bool ok0[8], ok2[8];
#pragma unroll
  for (int n = 0; n < 8; ++n) {
    const int p_out = wn * 128 + n * 16 + l15;   // 0..511
    const int r_out = p_out >> 5, c_out = p_out & 31;
    ok0[n] = (c_out >= 1);
    ok2[n] = (c_out <= 30);
#pragma unroll
    for (int dx = 0; dx < 3; ++dx) {
      const int c = c_out + dx - 1;
      const int cs = ((unsigned)c < 32u) ? c : c_out;   // safe fallback col
      const int row = r_out * 32 + cs;                  // +dy via +2048 (inv.)
      baddr[n][dx] = row * 64 + ((d ^ ((row >> 1) & 3)) << 4);
    }
  }

  // ---- W staging: single linear pointer into pre-arranged wb2 ----
  const unsigned short* wp = wb2 + (size_t)ct * 331776 + lane * 8;
#define WSTAGE(wo)                                                  \
  do {                                                              \
    gld16(wp + wv * 512,          lds + (wo) + wv * 1024);          \
    gld16(wp + wv * 512 + 2048,   lds + (wo) + wv * 1024 + 4096);   \
    gld16(wp + wv * 512 + 4096,   lds + (wo) + wv * 1024 + 8192);   \
    gld16(wp + wv * 512 + 6144,   lds + (wo) + wv * 1024 + 12288);  \
    if (wv < 2)                                                     \
      gld16(wp + wv * 512 + 8192, lds + (wo) + wv * 1024 + 16384);  \
    wp += 9216;                                                     \
  } while (0)

  // ---- IN staging: 36 slabs/chunk; step dy stages slabs dy*12 + wv + 4k ----
  const unsigned short* ip[9];
  int istep[9];
#pragma unroll
  for (int dy2 = 0; dy2 < 3; ++dy2) {
#pragma unroll
    for (int k = 0; k < 3; ++k) {
      const int j = dy2 * 3 + k;
      const int s = dy2 * 12 + wv + 4 * k;       // 0..35
      const int pix = s * 16 + (lane >> 2);      // 0..575
      const int prow = pix >> 5, pcol = pix & 31;
      const int h = h0 - 1 + prow;               // 18-row window
      const int dd = (lane & 3) ^ ((pix >> 1) & 3);
      if (h >= 0 && h < 32) {
        ip[j] = fea + ((size_t)((b * 32 + h) * 32 + pcol) * 384 + dd * 8);
        istep[j] = 32;
      } else {
        ip[j] = zpg + lane * 8;                  // stage zeros (h-edge)
        istep[j] = 0;
      }
    }
  }

  f32x4 acc[6][8] = {};
  const short8 z8 = {0, 0, 0, 0, 0, 0, 0, 0};
  short8 pf_af[6], pf_bf[8];

  // ---- prologue: W[0]->buf0, W[1]->buf1; IN chunk 0 -> ibuf0 ----
  WSTAGE(0);
  WSTAGE(18432);
#pragma unroll
  for (int j = 0; j < 9; ++j) {
    const int dy2 = j / 3, k = j - dy2 * 3;
    const int s = dy2 * 12 + wv + 4 * k;
    gld16(ip[j], lds + 55296 + s * 1024);
    ip[j] += istep[j];
  }
  __syncthreads();
  // prefetch af for step 0 (buf0, dx=0)
#pragma unroll
  for (int m = 0; m < 6; ++m)
    pf_af[m] = *reinterpret_cast<const short8*>(lds + m * 1024 + aoff);

  for (int cc = 0; cc < 12; ++cc) {
#pragma unroll
    for (int dy = 0; dy < 3; ++dy) {
      const int st = cc * 3 + dy;
      // compile-time buffer selects: st % 3 == dy
      const unsigned char* wbase = lds + dy * 18432;
      const unsigned char* wnext = lds + ((dy + 1) % 3) * 18432;
      const unsigned char* ibase = lds + 55296 + (cc & 1) * 36864;
      // stage W(st+2) into buf (dy+2)%3
      if (cc < 11 || dy == 0) WSTAGE(((dy + 2) % 3) * 18432);
      // stage IN(chunk cc+1), dy-th third, into the other IN buffer
      if (cc < 11) {
        const int io = 55296 + ((cc + 1) & 1) * 36864;
        const int s0 = dy * 12 + wv;
#pragma unroll
        for (int k = 0; k < 3; ++k) {
          const int j = dy * 3 + k;
          gld16(ip[j], lds + io + (s0 + 4 * k) * 1024);
          ip[j] += istep[j];
        }
      }
      // ---- compute 3 dx taps of (cc, dy) ----
#pragma unroll
      for (int dx = 0; dx < 3; ++dx) {
        short8 af[6], bf[8];
        if (dx == 0) {
#pragma unroll
          for (int m = 0; m < 6; ++m) af[m] = pf_af[m];
          if (dy == 0) {                         // bf fresh at chunk entry
#pragma unroll
            for (int n = 0; n < 8; ++n) {
              short8 v = *reinterpret_cast<const short8*>(ibase + baddr[n][0]);
              bf[n] = ok0[n] ? v : z8;
            }
          } else {
#pragma unroll
            for (int n = 0; n < 8; ++n) bf[n] = pf_bf[n];
          }
        } else {
#pragma unroll
          for (int m = 0; m < 6; ++m)
            af[m] = *reinterpret_cast<const short8*>(
                wbase + dx * 6144 + m * 1024 + aoff);
#pragma unroll
          for (int n = 0; n < 8; ++n) {
            short8 v = *reinterpret_cast<const short8*>(
                ibase + baddr[n][dx] + dy * 2048);
            if (dx == 2) v = ok2[n] ? v : z8;
            bf[n] = v;
          }
        }
#pragma unroll
        for (int m = 0; m < 6; ++m)
#pragma unroll
          for (int n = 0; n < 8; ++n)
            acc[m][n] = __builtin_amdgcn_mfma_f32_16x16x32_bf16(
                af[m], bf[n], acc[m][n], 0, 0, 0);
      }
      // ---- prefetch step st+1's dx=0 fragments (W[st+1] resident) ----
      if (st < 35) {
#pragma unroll
        for (int m = 0; m < 6; ++m)
          pf_af[m] = *reinterpret_cast<const short8*>(wnext + m * 1024 + aoff);
        if (dy < 2) {                            // st+1 in same IN chunk
#pragma unroll
          for (int n = 0; n < 8; ++n) {
            short8 v = *reinterpret_cast<const short8*>(
                ibase + baddr[n][0] + (dy + 1) * 2048);
            pf_bf[n] = ok0[n] ? v : z8;
          }
        }
      }
      __syncthreads();
    }
  }
#undef WSTAGE

  // ---- BN partial stats (no stores yet) ----
#pragma unroll
  for (int m = 0; m < 6; ++m) {
#pragma unroll
    for (int r = 0; r < 4; ++r) {
      const int co = m * 16 + d * 4 + r;     // within co tile
      float s = 0.f, q = 0.f;
#pragma unroll
      for (int n = 0; n < 8; ++n) {
        const float v = acc[m][n][r];
        s += v; q += v * v;
      }
#pragma unroll
      for (int off = 1; off < 16; off <<= 1) {
        s += __shfl_xor(s, off, 64);
        q += __shfl_xor(q, off, 64);
      }
      if (l15 == 0) {
        atomicAdd(&bn_sum[co0 + co], s);
        atomicAdd(&bn_sq[co0 + co], q);
      }
    }
  }

  // prefetch gamma/beta for this thread's co range before the spin
  float gpref = 0.f, bpref = 0.f;
  if (tid < 96) { gpref = gamma[co0 + tid]; bpref = beta[co0 + tid]; }

  // ---- group barrier: 64 blocks of this ct ----
  __threadfence();
  __syncthreads();
  if (tid == 0) atomicAdd(&ctr[ct], 1);
  if (tid == 0) {
    while (__hip_atomic_load(&ctr[ct], __ATOMIC_ACQUIRE,
                             __HIP_MEMORY_SCOPE_AGENT) < 64)
      __builtin_amdgcn_s_sleep(2);
  }
  __syncthreads();

  // ---- build per-co (rs, b') in LDS; normalize acc; store ----
  float* ls_rs = reinterpret_cast<float*>(lds);
  float* ls_bb = reinterpret_cast<float*>(lds + 512);
  if (tid < 96) {
    const int co = co0 + tid;
    const float sv = __hip_atomic_load(&bn_sum[co], __ATOMIC_RELAXED,
                                       __HIP_MEMORY_SCOPE_AGENT);
    const float qv = __hip_atomic_load(&bn_sq[co], __ATOMIC_RELAXED,
                                       __HIP_MEMORY_SCOPE_AGENT);
    const float inv = 1.0f / 32768.0f;
    const float mu = sv * inv;
    const float var = fmaxf(qv * inv - mu * mu, 0.0f);
    const float rs = rsqrtf(var + 1e-5f) * gpref;
    ls_rs[tid] = rs;
    ls_bb[tid] = bpref - mu * rs;
  }
  __syncthreads();

  const size_t ob = (((size_t)b * 384 + co0) << 10) + h0 * 32;
#pragma unroll
  for (int m = 0; m < 6; ++m) {
#pragma unroll
    for (int r = 0; r < 4; ++r) {
      const int co = m * 16 + d * 4 + r;
      const float rs = ls_rs[co], bb = ls_bb[co];
#pragma unroll
      for (int n = 0; n < 8; ++n) {
        const int p = wn * 128 + n * 16 + l15;  // 0..511 within 16-row strip
        out[ob + ((size_t)co << 10) + p] = acc[m][n][r] * rs + bb;
      }
    }
  }
}

extern "C" void kernel_launch(void* const* d_in, const int* in_sizes, int n_in,
                              void* d_out, int out_size, void* d_ws, size_t ws_size,
                              hipStream_t stream) {
  const float* x     = (const float*)d_in[0];
  const float* pmp   = (const float*)d_in[1];
  const float* psp   = (const float*)d_in[2];
  const float* pmn   = (const float*)d_in[3];
  const float* psn   = (const float*)d_in[4];
  const float* cw    = (const float*)d_in[5];
  const float* convw = (const float*)d_in[6];
  const float* gamma = (const float*)d_in[7];
  const float* beta  = (const float*)d_in[8];
  const int*   label = (const int*)d_in[9];
  float* out = (float*)d_out;
  char* ws = (char*)d_ws;

  // ws layout (~28 MB total)
  unsigned short* fea = (unsigned short*)(ws);                 // 25165824 B
  unsigned short* wb2 = (unsigned short*)(ws + 25165824);      //  2654208 B
  float* sums  = (float*)(ws + 27820032);                      //    49152 B
  float* sumsq = (float*)(ws + 27869184);                      //    49152 B
  float* bn    = (float*)(ws + 28016640);                      //     3072 B
  float* zp    = (float*)(ws + 28019712);                      //     4096 B
  int*   ctr   = (int*)(ws + 28023808);                        //       16 B

  k_stats<<<dim3(12936), dim3(256), 0, stream>>>(x, sums, sumsq, bn, ctr, zp,
                                                 convw, wb2);
  k_fea<<<dim3(128, 6), dim3(256), 0, stream>>>(x, pmp, psp, pmn, psn, cw,
                                                label, sums, sumsq, fea);
  k_conv<<<dim3(64, 4), dim3(256), 0, stream>>>(fea, wb2, (const unsigned short*)zp,
                                                out, bn, bn + 384, gamma, beta, ctr);
}